// Round 6
// baseline (160.507 us; speedup 1.0000x reference)
//
#include <hip/hip_runtime.h>

#define HW   112
#define PH   114            // padded plane dim
#define KK   576
#define PLANE_SH (8 * PH * PH * 64)        // shorts per power plane
#define PLANE_B  (PLANE_SH * 2)            // bytes per plane
#define WB_OFF_SH (3 * PLANE_SH)
#define S_OFF_SH  (WB_OFF_SH + 36864)
// ws_size needed: ~40 MB

typedef __attribute__((ext_vector_type(8))) short s16x8;
typedef __attribute__((ext_vector_type(4))) float f32x4;
typedef __attribute__((ext_vector_type(2))) float f32x2;

__device__ inline unsigned short f2bf(float f) {
    unsigned u = __float_as_uint(f);
    u += 0x7FFF + ((u >> 16) & 1);            // RNE
    return (unsigned short)(u >> 16);
}

// ---- pass 1a: border zeros + weight transpose + row sums, one kernel ----
// Wb flat index: (((tap*2 + cc)*4 + nt)*64 + lane)*8 + j
//   k = cc*32 + (lane>>4)*8 + j, n = nt*16 + (lane&15), value = W[n][k*9 + tap]
__global__ void prep_all(const float* __restrict__ W,
                         unsigned short* __restrict__ pw,
                         unsigned short* __restrict__ wb,
                         float* __restrict__ S) {
    __shared__ float partial[256];
    const int bid = blockIdx.x, t = threadIdx.x;
    if (bid < 24) {                          // border zeros: 3p * 8b
        const int p = bid >> 3, b = bid & 7;
        unsigned short* base = pw + (size_t)p * PLANE_SH + (size_t)b * PH * PH * 64;
        const s16x8 z = {0, 0, 0, 0, 0, 0, 0, 0};
        for (int i = 0; i < 15; ++i) {
            const int e = t + i * 256;
            if (e >= 3616) break;            // 452 border px * 8 c-octs
            const int n = e >> 3, c8 = e & 7;
            int x, yy;
            if (n < 114)      { yy = 0;   x = n; }
            else if (n < 228) { yy = 113; x = n - 114; }
            else { const int m2 = n - 228; yy = 1 + (m2 >> 1); x = (m2 & 1) ? 113 : 0; }
            *(s16x8*)&base[(yy * PH + x) * 64 + c8 * 8] = z;
        }
    } else if (bid < 168) {                  // weight transpose: 144 blocks
        const int i   = (bid - 24) * 256 + t;
        const int j   = i & 7;
        const int l   = (i >> 3) & 63;
        const int nt  = (i >> 9) & 3;
        const int cc  = (i >> 11) & 1;
        const int tap = i >> 12;
        const int c   = cc * 32 + ((l >> 4) << 3) + j;
        const int o   = nt * 16 + (l & 15);
        wb[i] = f2bf(W[o * KK + c * 9 + tap]);
    } else {                                 // row sums
        const int o = t >> 2, part = t & 3;
        const float4* row = (const float4*)(W + o * KK) + part * 36;
        float s = 0.f;
        for (int k = 0; k < 36; ++k) { float4 v = row[k]; s += v.x + v.y + v.z + v.w; }
        partial[t] = s;
        __syncthreads();
        if (part == 0) S[o] = partial[t] + partial[t + 1] + partial[t + 2] + partial[t + 3];
    }
}

// ---- pass 1b: NCHW fp32 -> padded NHWC bf16 planes of v, v^2, v^3 ----
__global__ __launch_bounds__(256) void pow_kernel(const float* __restrict__ img,
                                                  unsigned short* __restrict__ pw) {
    __shared__ __align__(16) unsigned short sA[3 * 112 * 72];   // [p][x][c pad 72]
    const int t = threadIdx.x;
    const int bid = blockIdx.x;              // 896 = 8b * 112y
    const int b = bid / 112, y = bid - b * 112;

    const int c = t & 63, xq0 = t >> 6;
    const float4* src = (const float4*)(img + (((size_t)(b * 64 + c) * HW + y) * HW));
    #pragma unroll
    for (int i = 0; i < 7; ++i) {
        const int xq = xq0 + i * 4;
        const float4 v = src[xq];
        const float vv[4] = {v.x, v.y, v.z, v.w};
        #pragma unroll
        for (int u = 0; u < 4; ++u) {
            const float v1 = vv[u], v2 = v1 * v1, v3 = v2 * v1;
            const int x = xq * 4 + u;
            sA[x * 72 + c]         = f2bf(v1);
            sA[8064 + x * 72 + c]  = f2bf(v2);
            sA[16128 + x * 72 + c] = f2bf(v3);
        }
    }
    __syncthreads();

    for (int i = 0; i < 11; ++i) {
        const int ch = t + i * 256;
        if (ch >= 2688) break;               // 3p * 112x * 8 c-octs
        const int p = ch / 896, r = ch - p * 896;
        const int x = r >> 3, c8 = r & 7;
        const s16x8 val = *(const s16x8*)&sA[p * 8064 + x * 72 + c8 * 8];
        *(s16x8*)&pw[(size_t)p * PLANE_SH + ((size_t)(b * PH + y + 1) * PH + (x + 1)) * 64 + c8 * 8] = val;
    }
}

// ---- pass 2: implicit-GEMM conv, register double-buffered A+B pipeline ----
// wave = 2 rows x 16 px x 32 oc: rowg = wv&1, ocg = wv>>1
__global__ __launch_bounds__(256, 2) void conv_main(const unsigned short* __restrict__ pw,
                                                    const unsigned short* __restrict__ wb,
                                                    const float* __restrict__ S,
                                                    float* __restrict__ out) {
    const int t = threadIdx.x, wv = t >> 6, lane = t & 63;
    const int m = lane & 15, q = lane >> 4;
    const int rowg = wv & 1, ocg = wv >> 1;

    const int bid = blockIdx.x;       // 1568: b = bid&7 (XCD/L2 affinity)
    const int b = bid & 7;
    const int r = bid >> 3;           // 0..195 = 28 ty * 7 tx
    const int ty = r / 7, tx = r - ty * 7;
    const int Y0 = ty * 4 + rowg * 2; // this wave's output rows: Y0, Y0+1
    const int X0 = tx * 16;

    f32x4 acc[3][2][2];               // [power][at][ntl]
    #pragma unroll
    for (int p = 0; p < 3; ++p)
        #pragma unroll
        for (int at = 0; at < 2; ++at)
            #pragma unroll
            for (int ntl = 0; ntl < 2; ++ntl)
                acc[p][at][ntl] = (f32x4){0.f, 0.f, 0.f, 0.f};

    const char* pb = (const char*)(pw + (size_t)b * PH * PH * 64);
    int vofs[4];
    #pragma unroll
    for (int r4 = 0; r4 < 4; ++r4)
        vofs[r4] = ((Y0 + r4) * PH + X0 + m) * 128 + q * 16;   // row Y0+r4 serves (at,ky): at+ky==r4

    // register double-buffers (indices constant after full unroll)
    s16x8 afb[2][4][3];               // [buf][row][power]
    s16x8 bfb[2][3][2];               // [buf][ky][ntl]

    // prologue: loads for idx 0 = (cc0, kx0). B first, then A (order irrelevant here).
    #pragma unroll
    for (int ky = 0; ky < 3; ++ky)
        #pragma unroll
        for (int ntl = 0; ntl < 2; ++ntl)
            bfb[0][ky][ntl] = *(const s16x8*)&wb[((((ky * 3) * 2 + 0) * 4 + (ocg * 2 + ntl)) * 64 + lane) * 8];
    #pragma unroll
    for (int r4 = 0; r4 < 4; ++r4)
        #pragma unroll
        for (int p = 0; p < 3; ++p)
            afb[0][r4][p] = *(const s16x8*)(pb + (size_t)p * PLANE_B + vofs[r4]);

    #pragma unroll
    for (int idx = 0; idx < 6; ++idx) {
        const int cc  = (idx < 3) ? 0 : 1;
        const int kx  = (idx < 3) ? idx : idx - 3;
        const int cur = idx & 1, nxt = cur ^ 1;
        (void)cc; (void)kx;

        // prefetch ALL of next iteration's fragments BEFORE this iteration's MFMAs,
        // so the MFMA waitcnt is vmcnt(18) with next loads still in flight (in-order vmcnt).
        if (idx < 5) {
            const int nidx = idx + 1;
            const int ncc  = (nidx < 3) ? 0 : 1;
            const int nkx  = (nidx < 3) ? nidx : nidx - 3;
            #pragma unroll
            for (int ky = 0; ky < 3; ++ky)
                #pragma unroll
                for (int ntl = 0; ntl < 2; ++ntl)
                    bfb[nxt][ky][ntl] = *(const s16x8*)&wb[((((ky * 3 + nkx) * 2 + ncc) * 4 + (ocg * 2 + ntl)) * 64 + lane) * 8];
            #pragma unroll
            for (int r4 = 0; r4 < 4; ++r4)
                #pragma unroll
                for (int p = 0; p < 3; ++p)
                    afb[nxt][r4][p] = *(const s16x8*)(pb + (size_t)p * PLANE_B + vofs[r4] + nkx * 128 + ncc * 64);
        }

        // 36 MFMA on current buffers
        #pragma unroll
        for (int ky = 0; ky < 3; ++ky)
            #pragma unroll
            for (int at = 0; at < 2; ++at)
                #pragma unroll
                for (int p = 0; p < 3; ++p)
                    #pragma unroll
                    for (int ntl = 0; ntl < 2; ++ntl)
                        acc[p][at][ntl] = __builtin_amdgcn_mfma_f32_16x16x32_bf16(
                            afb[cur][at + ky][p], bfb[cur][ky][ntl], acc[p][at][ntl], 0, 0, 0);
    }

    // ---- epilogue: telescoped diffs; D layout n = lane&15, pixel m' = q*4 + reg ----
    #pragma unroll
    for (int ntl = 0; ntl < 2; ++ntl) {
        const int o = (ocg * 2 + ntl) * 16 + (lane & 15);
        const float Sv = S[o];
        const float fS = -0.000287f / 75.f * Sv;
        const float cg1 = 0.8448f  + 0.001309f * Sv;
        const float D1  = 0.52992f - 0.003809f * Sv;
        const float D2  = 0.45312f + 0.001546f * Sv;
        const float D3  = 1.152f   - 0.006386f * Sv;
        const float D4  = 0.91392f - 0.00283f  * Sv;
        #pragma unroll
        for (int at = 0; at < 2; ++at) {
            float res[4];
            #pragma unroll
            for (int h = 0; h < 2; ++h) {
                const f32x2 u1 = {acc[0][at][ntl][2 * h], acc[0][at][ntl][2 * h + 1]};
                const f32x2 u2 = {acc[1][at][ntl][2 * h], acc[1][at][ntl][2 * h + 1]};
                const f32x2 u3 = {acc[2][at][ntl][2 * h], acc[2][at][ntl][2 * h + 1]};
                const f32x2 f  = fS   + 0.00354667f * u1 - 0.00146267f * u2;
                const f32x2 g1 = cg1  + 0.00619f    * u1 - 0.009f      * u2 + 0.001383f * u3;
                const f32x2 d1 = D1   - 0.00316f    * u1 + 0.00416f    * u2 + 0.016117f * u3;
                const f32x2 d2 = D2   - 0.00116f    * u1 + 0.006717f   * u2 - 0.00248f  * u3;
                const f32x2 d3 = D3   - 0.000753f   * u1 + 0.005643f   * u2 - 0.00602f  * u3;
                const f32x2 d4 = D4   - 0.000691f   * u1 + 0.00085f    * u2 - 0.00487f  * u3;
                f32x2 E;
                E.x = __expf(-10.f * f.x);
                E.y = __expf(-10.f * f.y);
                const f32x2 den1 = 1.f + E * 4.4816890703f;
                const f32x2 den2 = 1.f + E * 9.9741824548f;
                const f32x2 den3 = 1.f + E * 24.5325301971f;
                const f32x2 den4 = 1.f + E * 49.4024491055f;
                f32x2 o2 = g1;
                o2.x += __builtin_amdgcn_rcpf(den1.x) * d1.x + __builtin_amdgcn_rcpf(den2.x) * d2.x
                      + __builtin_amdgcn_rcpf(den3.x) * d3.x + __builtin_amdgcn_rcpf(den4.x) * d4.x;
                o2.y += __builtin_amdgcn_rcpf(den1.y) * d1.y + __builtin_amdgcn_rcpf(den2.y) * d2.y
                      + __builtin_amdgcn_rcpf(den3.y) * d3.y + __builtin_amdgcn_rcpf(den4.y) * d4.y;
                res[2 * h] = o2.x; res[2 * h + 1] = o2.y;
            }
            const int y = Y0 + at;
            float* op = out + (((size_t)(b * 64 + o)) * HW + y) * HW + X0 + q * 4;
            *(float4*)op = make_float4(res[0], res[1], res[2], res[3]);
        }
    }
}

extern "C" void kernel_launch(void* const* d_in, const int* in_sizes, int n_in,
                              void* d_out, int out_size, void* d_ws, size_t ws_size,
                              hipStream_t stream) {
    const float* img = (const float*)d_in[0];
    const float* w   = (const float*)d_in[1];
    float* outp = (float*)d_out;
    unsigned short* pw = (unsigned short*)d_ws;
    unsigned short* wb = pw + WB_OFF_SH;
    float* S = (float*)(pw + S_OFF_SH);

    hipLaunchKernelGGL(prep_all,   dim3(169),  dim3(256), 0, stream, w, pw, wb, S);
    hipLaunchKernelGGL(pow_kernel, dim3(896),  dim3(256), 0, stream, img, pw);
    hipLaunchKernelGGL(conv_main,  dim3(1568), dim3(256), 0, stream, pw, wb, S, outp);
}

// Round 7
// 120.883 us; speedup vs baseline: 1.3278x; 1.3278x over previous
//
#include <hip/hip_runtime.h>

#define HW   112
#define PH   114            // padded plane dim
#define KK   576
#define ROWB (PH * 128)                    // bytes per padded NHWC row = 14592
#define PLANE_SH (8 * PH * PH * 64)        // shorts per power plane
#define PLANE_B  (PLANE_SH * 2)            // bytes per plane
#define WB_OFF_SH (3 * PLANE_SH)
#define S_OFF_SH  (WB_OFF_SH + 36864)
// ws_size needed: ~40 MB

typedef __attribute__((ext_vector_type(8))) short s16x8;
typedef __attribute__((ext_vector_type(4))) float f32x4;
typedef __attribute__((ext_vector_type(2))) float f32x2;
typedef __attribute__((address_space(3))) unsigned int lds_u32;
typedef const __attribute__((address_space(1))) unsigned int glb_u32;

__device__ inline unsigned short f2bf(float f) {
    unsigned u = __float_as_uint(f);
    u += 0x7FFF + ((u >> 16) & 1);            // RNE
    return (unsigned short)(u >> 16);
}

// ---- pass 1a: border zeros + weight transpose + row sums ----
// Wb flat index: (((tap*2 + cc)*4 + nt)*64 + lane)*8 + j
//   k = cc*32 + (lane>>4)*8 + j, n = nt*16 + (lane&15), value = W[n][k*9 + tap]
__global__ void prep_all(const float* __restrict__ W,
                         unsigned short* __restrict__ pw,
                         unsigned short* __restrict__ wb,
                         float* __restrict__ S) {
    __shared__ float partial[256];
    const int bid = blockIdx.x, t = threadIdx.x;
    if (bid < 24) {                          // border zeros: 3p * 8b
        const int p = bid >> 3, b = bid & 7;
        unsigned short* base = pw + (size_t)p * PLANE_SH + (size_t)b * PH * PH * 64;
        const s16x8 z = {0, 0, 0, 0, 0, 0, 0, 0};
        for (int i = 0; i < 15; ++i) {
            const int e = t + i * 256;
            if (e >= 3616) break;            // 452 border px * 8 c-octs
            const int n = e >> 3, c8 = e & 7;
            int x, yy;
            if (n < 114)      { yy = 0;   x = n; }
            else if (n < 228) { yy = 113; x = n - 114; }
            else { const int m2 = n - 228; yy = 1 + (m2 >> 1); x = (m2 & 1) ? 113 : 0; }
            *(s16x8*)&base[(yy * PH + x) * 64 + c8 * 8] = z;
        }
    } else if (bid < 168) {                  // weight transpose
        const int i   = (bid - 24) * 256 + t;
        const int j   = i & 7;
        const int l   = (i >> 3) & 63;
        const int nt  = (i >> 9) & 3;
        const int cc  = (i >> 11) & 1;
        const int tap = i >> 12;
        const int c   = cc * 32 + ((l >> 4) << 3) + j;
        const int o   = nt * 16 + (l & 15);
        wb[i] = f2bf(W[o * KK + c * 9 + tap]);
    } else {                                 // row sums
        const int o = t >> 2, part = t & 3;
        const float4* row = (const float4*)(W + o * KK) + part * 36;
        float s = 0.f;
        for (int k = 0; k < 36; ++k) { float4 v = row[k]; s += v.x + v.y + v.z + v.w; }
        partial[t] = s;
        __syncthreads();
        if (part == 0) S[o] = partial[t] + partial[t + 1] + partial[t + 2] + partial[t + 3];
    }
}

// ---- pass 1b: NCHW fp32 -> padded NHWC bf16 planes of v, v^2, v^3 ----
__global__ __launch_bounds__(256) void pow_kernel(const float* __restrict__ img,
                                                  unsigned short* __restrict__ pw) {
    __shared__ __align__(16) unsigned short sA[3 * 112 * 72];   // [p][x][c pad 72]
    const int t = threadIdx.x;
    const int bid = blockIdx.x;              // 896 = 8b * 112y
    const int b = bid / 112, y = bid - b * 112;

    const int c = t & 63, xq0 = t >> 6;
    const float4* src = (const float4*)(img + (((size_t)(b * 64 + c) * HW + y) * HW));
    #pragma unroll
    for (int i = 0; i < 7; ++i) {
        const int xq = xq0 + i * 4;
        const float4 v = src[xq];
        const float vv[4] = {v.x, v.y, v.z, v.w};
        #pragma unroll
        for (int u = 0; u < 4; ++u) {
            const float v1 = vv[u], v2 = v1 * v1, v3 = v2 * v1;
            const int x = xq * 4 + u;
            sA[x * 72 + c]         = f2bf(v1);
            sA[8064 + x * 72 + c]  = f2bf(v2);
            sA[16128 + x * 72 + c] = f2bf(v3);
        }
    }
    __syncthreads();

    for (int i = 0; i < 11; ++i) {
        const int ch = t + i * 256;
        if (ch >= 2688) break;               // 3p * 112x * 8 c-octs
        const int p = ch / 896, r = ch - p * 896;
        const int x = r >> 3, c8 = r & 7;
        const s16x8 val = *(const s16x8*)&sA[p * 8064 + x * 72 + c8 * 8];
        *(s16x8*)&pw[(size_t)p * PLANE_SH + ((size_t)(b * PH + y + 1) * PH + (x + 1)) * 64 + c8 * 8] = val;
    }
}

// ---- pass 2: m97-style conv: LDS-staged A (swizzled), global B, MFMA ----
// block = 256 thr (4 waves), tile = 8 rows x 16 px x 64 oc; wave wv: rows 2wv, 2wv+1
// LDS per cc-half: [p][row 10][px 18][c8s 4] 16B granules, swizzle c8s = c8 ^ (px&3) ^ ((px>>2)&3)
#define LP_PLANE 11520                     // bytes per plane in LDS (10*18*64)
#define LP_ROW   1152
#define STAGE_B  34560                     // 3 * LP_PLANE

__global__ __launch_bounds__(256, 2) void conv_main(const unsigned short* __restrict__ pw,
                                                    const unsigned short* __restrict__ wb,
                                                    const float* __restrict__ S,
                                                    float* __restrict__ out) {
    __shared__ __align__(16) char tile[STAGE_B];

    const int t = threadIdx.x, wv = t >> 6, lane = t & 63;
    const int m = lane & 15, q = lane >> 4;

    const int bid = blockIdx.x;       // 784: b = bid&7 (XCD/L2 affinity)
    const int b = bid & 7;
    const int r = bid >> 3;           // 0..97 = 14 ty * 7 tx
    const int ty = r / 7, tx = r - ty * 7;
    const int y0 = ty * 8, x0 = tx * 16;

    f32x4 acc[3][2][4];               // [power][at][nt]
    #pragma unroll
    for (int p = 0; p < 3; ++p)
        #pragma unroll
        for (int at = 0; at < 2; ++at)
            #pragma unroll
            for (int nt = 0; nt < 4; ++nt)
                acc[p][at][nt] = (f32x4){0.f, 0.f, 0.f, 0.f};

    // global base of this block's window (padded coords, top-left = (y0, x0))
    const char* pwin = (const char*)pw + ((size_t)(b * PH + y0) * PH + x0) * 128;

    #pragma unroll 1
    for (int cc = 0; cc < 2; ++cc) {
        if (cc) __syncthreads();      // WAR: prior reads done before restage
        // ---- stage: 34,560 B, lane-linear LDS dest, swizzled source pick ----
        #pragma unroll
        for (int i = 0; i < 9; ++i) {
            const int f = i * 4096 + t * 16;
            if (f < STAGE_B) {
                const int p   = f / LP_PLANE;
                const int r1  = f - p * LP_PLANE;
                const int row = r1 / LP_ROW;
                const int r2  = r1 - row * LP_ROW;
                const int px  = r2 >> 6;
                const int c8s = (r2 >> 4) & 3;
                const int c8  = c8s ^ (px & 3) ^ ((px >> 2) & 3);
                const char* gp = pwin + (size_t)p * PLANE_B + row * ROWB + px * 128 + cc * 64 + c8 * 16;
                lds_u32* lp = (lds_u32*)(tile + i * 4096 + wv * 1024);
                __builtin_amdgcn_global_load_lds((glb_u32*)gp, lp, 16, 0, 0);
            }
        }
        __syncthreads();

        // ---- 3 kx-steps: 12 B global loads + 12 A ds_reads + 72 MFMA ----
        #pragma unroll
        for (int kx = 0; kx < 3; ++kx) {
            s16x8 bf[3][4];
            #pragma unroll
            for (int ky = 0; ky < 3; ++ky) {
                const int tap = ky * 3 + kx;
                #pragma unroll
                for (int nt = 0; nt < 4; ++nt)
                    bf[ky][nt] = *(const s16x8*)&wb[(((tap * 2 + cc) * 4 + nt) * 64 + lane) * 8];
            }
            const int pxr  = m + kx;
            const int c8sr = q ^ (pxr & 3) ^ ((pxr >> 2) & 3);
            const int abase = wv * (2 * LP_ROW) + pxr * 64 + c8sr * 16;
            s16x8 af[4][3];
            #pragma unroll
            for (int r4 = 0; r4 < 4; ++r4)
                #pragma unroll
                for (int p = 0; p < 3; ++p)
                    af[r4][p] = *(const s16x8*)&tile[abase + r4 * LP_ROW + p * LP_PLANE];
            #pragma unroll
            for (int ky = 0; ky < 3; ++ky)
                #pragma unroll
                for (int at = 0; at < 2; ++at)
                    #pragma unroll
                    for (int p = 0; p < 3; ++p)
                        #pragma unroll
                        for (int nt = 0; nt < 4; ++nt)
                            acc[p][at][nt] = __builtin_amdgcn_mfma_f32_16x16x32_bf16(
                                af[at + ky][p], bf[ky][nt], acc[p][at][nt], 0, 0, 0);
        }
    }

    // ---- epilogue: telescoped diffs, f32x2 packed; D: n = lane&15, px = q*4+reg ----
    #pragma unroll
    for (int nt = 0; nt < 4; ++nt) {
        const int o = nt * 16 + (lane & 15);
        const float Sv = S[o];
        const float fS = -0.000287f / 75.f * Sv;
        const float cg1 = 0.8448f  + 0.001309f * Sv;
        const float D1  = 0.52992f - 0.003809f * Sv;
        const float D2  = 0.45312f + 0.001546f * Sv;
        const float D3  = 1.152f   - 0.006386f * Sv;
        const float D4  = 0.91392f - 0.00283f  * Sv;
        #pragma unroll
        for (int at = 0; at < 2; ++at) {
            float res[4];
            #pragma unroll
            for (int h = 0; h < 2; ++h) {
                const f32x2 u1 = {acc[0][at][nt][2 * h], acc[0][at][nt][2 * h + 1]};
                const f32x2 u2 = {acc[1][at][nt][2 * h], acc[1][at][nt][2 * h + 1]};
                const f32x2 u3 = {acc[2][at][nt][2 * h], acc[2][at][nt][2 * h + 1]};
                const f32x2 f  = fS   + 0.00354667f * u1 - 0.00146267f * u2;
                const f32x2 g1 = cg1  + 0.00619f    * u1 - 0.009f      * u2 + 0.001383f * u3;
                const f32x2 d1 = D1   - 0.00316f    * u1 + 0.00416f    * u2 + 0.016117f * u3;
                const f32x2 d2 = D2   - 0.00116f    * u1 + 0.006717f   * u2 - 0.00248f  * u3;
                const f32x2 d3 = D3   - 0.000753f   * u1 + 0.005643f   * u2 - 0.00602f  * u3;
                const f32x2 d4 = D4   - 0.000691f   * u1 + 0.00085f    * u2 - 0.00487f  * u3;
                f32x2 E;
                E.x = __expf(-10.f * f.x);
                E.y = __expf(-10.f * f.y);
                const f32x2 den1 = 1.f + E * 4.4816890703f;
                const f32x2 den2 = 1.f + E * 9.9741824548f;
                const f32x2 den3 = 1.f + E * 24.5325301971f;
                const f32x2 den4 = 1.f + E * 49.4024491055f;
                f32x2 o2 = g1;
                o2.x += __builtin_amdgcn_rcpf(den1.x) * d1.x + __builtin_amdgcn_rcpf(den2.x) * d2.x
                      + __builtin_amdgcn_rcpf(den3.x) * d3.x + __builtin_amdgcn_rcpf(den4.x) * d4.x;
                o2.y += __builtin_amdgcn_rcpf(den1.y) * d1.y + __builtin_amdgcn_rcpf(den2.y) * d2.y
                      + __builtin_amdgcn_rcpf(den3.y) * d3.y + __builtin_amdgcn_rcpf(den4.y) * d4.y;
                res[2 * h] = o2.x; res[2 * h + 1] = o2.y;
            }
            const int y = y0 + 2 * wv + at;
            float* op = out + (((size_t)(b * 64 + o)) * HW + y) * HW + x0 + q * 4;
            *(float4*)op = make_float4(res[0], res[1], res[2], res[3]);
        }
    }
}

extern "C" void kernel_launch(void* const* d_in, const int* in_sizes, int n_in,
                              void* d_out, int out_size, void* d_ws, size_t ws_size,
                              hipStream_t stream) {
    const float* img = (const float*)d_in[0];
    const float* w   = (const float*)d_in[1];
    float* outp = (float*)d_out;
    unsigned short* pw = (unsigned short*)d_ws;
    unsigned short* wb = pw + WB_OFF_SH;
    float* S = (float*)(pw + S_OFF_SH);

    hipLaunchKernelGGL(prep_all,   dim3(169), dim3(256), 0, stream, w, pw, wb, S);
    hipLaunchKernelGGL(pow_kernel, dim3(896), dim3(256), 0, stream, img, pw);
    hipLaunchKernelGGL(conv_main,  dim3(784), dim3(256), 0, stream, pw, wb, S, outp);
}

// Round 9
// 114.370 us; speedup vs baseline: 1.4034x; 1.0569x over previous
//
#include <hip/hip_runtime.h>

#define HW   112
#define PH   114            // padded plane dim
#define KK   576
#define ROWB (PH * 128)                    // bytes per padded NHWC row
#define PLANE_SH (8 * PH * PH * 64)        // shorts per power plane
#define PLANE_B  (PLANE_SH * 2)            // bytes per plane
#define WB_OFF_SH (3 * PLANE_SH)
#define S_OFF_SH  (WB_OFF_SH + 36864)
// ws_size needed: ~40 MB

typedef __attribute__((ext_vector_type(8))) short s16x8;
typedef __attribute__((ext_vector_type(4))) float f32x4;
typedef __attribute__((ext_vector_type(2))) float f32x2;
typedef __attribute__((address_space(3))) unsigned int lds_u32;
typedef const __attribute__((address_space(1))) unsigned int glb_u32;

__device__ inline unsigned short f2bf(float f) {
    unsigned u = __float_as_uint(f);
    u += 0x7FFF + ((u >> 16) & 1);            // RNE
    return (unsigned short)(u >> 16);
}

// ---- pass 1 (fused): pow planes + border zeros + weight transpose + row sums ----
// Wb flat index: (((tap*2 + cc)*4 + nt)*64 + lane)*8 + j
//   k = cc*32 + (lane>>4)*8 + j, n = nt*16 + (lane&15), value = W[n][k*9 + tap]
__global__ __launch_bounds__(256) void prep_pow(const float* __restrict__ img,
                                                const float* __restrict__ W,
                                                unsigned short* __restrict__ pw,
                                                unsigned short* __restrict__ wb,
                                                float* __restrict__ S) {
    __shared__ __align__(16) unsigned short sA[3 * 112 * 72];   // [p][x][c pad 72]
    const int bid = blockIdx.x, t = threadIdx.x;
    if (bid < 896) {                         // pow: 8b * 112y
        const int b = bid / 112, y = bid - b * 112;
        const int c = t & 63, xq0 = t >> 6;
        const float4* src = (const float4*)(img + (((size_t)(b * 64 + c) * HW + y) * HW));
        #pragma unroll
        for (int i = 0; i < 7; ++i) {
            const int xq = xq0 + i * 4;
            const float4 v = src[xq];
            const float vv[4] = {v.x, v.y, v.z, v.w};
            #pragma unroll
            for (int u = 0; u < 4; ++u) {
                const float v1 = vv[u], v2 = v1 * v1, v3 = v2 * v1;
                const int x = xq * 4 + u;
                sA[x * 72 + c]         = f2bf(v1);
                sA[8064 + x * 72 + c]  = f2bf(v2);
                sA[16128 + x * 72 + c] = f2bf(v3);
            }
        }
        __syncthreads();
        for (int i = 0; i < 11; ++i) {
            const int ch = t + i * 256;
            if (ch >= 2688) break;           // 3p * 112x * 8 c-octs
            const int p = ch / 896, r = ch - p * 896;
            const int x = r >> 3, c8 = r & 7;
            const s16x8 val = *(const s16x8*)&sA[p * 8064 + x * 72 + c8 * 8];
            *(s16x8*)&pw[(size_t)p * PLANE_SH + ((size_t)(b * PH + y + 1) * PH + (x + 1)) * 64 + c8 * 8] = val;
        }
    } else if (bid < 920) {                  // border zeros: 3p * 8b
        const int k = bid - 896;
        const int p = k >> 3, b = k & 7;
        unsigned short* base = pw + (size_t)p * PLANE_SH + (size_t)b * PH * PH * 64;
        const s16x8 z = {0, 0, 0, 0, 0, 0, 0, 0};
        for (int i = 0; i < 15; ++i) {
            const int e = t + i * 256;
            if (e >= 3616) break;            // 452 border px * 8 c-octs
            const int n = e >> 3, c8 = e & 7;
            int x, yy;
            if (n < 114)      { yy = 0;   x = n; }
            else if (n < 228) { yy = 113; x = n - 114; }
            else { const int m2 = n - 228; yy = 1 + (m2 >> 1); x = (m2 & 1) ? 113 : 0; }
            *(s16x8*)&base[(yy * PH + x) * 64 + c8 * 8] = z;
        }
    } else if (bid < 1064) {                 // weight transpose: 144 blocks
        const int i   = (bid - 920) * 256 + t;
        const int j   = i & 7;
        const int l   = (i >> 3) & 63;
        const int nt  = (i >> 9) & 3;
        const int cc  = (i >> 11) & 1;
        const int tap = i >> 12;
        const int c   = cc * 32 + ((l >> 4) << 3) + j;
        const int o   = nt * 16 + (l & 15);
        wb[i] = f2bf(W[o * KK + c * 9 + tap]);
    } else {                                 // row sums
        __shared__ float partial[256];
        const int o = t >> 2, part = t & 3;
        const float4* row = (const float4*)(W + o * KK) + part * 36;
        float s = 0.f;
        for (int k = 0; k < 36; ++k) { float4 v = row[k]; s += v.x + v.y + v.z + v.w; }
        partial[t] = s;
        __syncthreads();
        if (part == 0) S[o] = partial[t] + partial[t + 1] + partial[t + 2] + partial[t + 3];
    }
}

// ---- pass 2: conv, fully LDS-fed K-loop, oc split across blocks ----
// block = 256 thr (4 waves), tile = 8 rows x 16 px x 32 oc; wave wv: rows 2wv, 2wv+1
// A LDS: [p][row 10][px 18][c8s 4] granules, swizzle c8s = c8 ^ (px&3) ^ ((px>>2)&3)
// W LDS: 18 chunks of 1KB, chunk = tap*2 + ntl   (this block's oc-half, this cc)
#define LP_PLANE 11520
#define LP_ROW   1152
#define STAGE_B  34560                     // 3 * LP_PLANE
#define WH_B     18432                     // 9 taps * 2 ntl * 1024

__global__ __launch_bounds__(256, 3) void conv_main(const unsigned short* __restrict__ pw,
                                                    const unsigned short* __restrict__ wb,
                                                    const float* __restrict__ S,
                                                    float* __restrict__ out) {
    __shared__ __align__(16) char ldsw[WH_B];
    __shared__ __align__(16) char tile[STAGE_B];   // total 52,992 B -> 3 blocks/CU

    const int t = threadIdx.x, wv = t >> 6, lane = t & 63;
    const int m = lane & 15, q = lane >> 4;

    const int bid = blockIdx.x;       // 1568: b = bid&7 (XCD pin); oc-half pairs adjacent
    const int b = bid & 7;
    const int rest = bid >> 3;        // 0..195
    const int oc2 = rest & 1;
    const int r = rest >> 1;          // 0..97 = 14 ty * 7 tx
    const int ty = r / 7, tx = r - ty * 7;
    const int y0 = ty * 8, x0 = tx * 16;

    f32x4 acc[3][2][2];               // [power][at][ntl]
    #pragma unroll
    for (int p = 0; p < 3; ++p)
        #pragma unroll
        for (int at = 0; at < 2; ++at)
            #pragma unroll
            for (int ntl = 0; ntl < 2; ++ntl)
                acc[p][at][ntl] = (f32x4){0.f, 0.f, 0.f, 0.f};

    const char* pwin = (const char*)pw + ((size_t)(b * PH + y0) * PH + x0) * 128;

    #pragma unroll 1
    for (int cc = 0; cc < 2; ++cc) {
        if (cc) __syncthreads();      // WAR: prior reads done before restage
        // ---- stage weights: 18,432 B; LDS chunk lchunk = i*4+wv = tap*2+ntl ----
        #pragma unroll
        for (int i = 0; i < 5; ++i) {
            const int f = i * 4096 + t * 16;
            if (f < WH_B) {
                const int lchunk = f >> 10;          // wave-uniform: i*4 + wv
                const int tap = lchunk >> 1, ntl = lchunk & 1;
                const char* gp = (const char*)wb
                    + ((size_t)((tap * 2 + cc) * 4 + oc2 * 2 + ntl)) * 1024 + lane * 16;
                lds_u32* lp = (lds_u32*)(ldsw + i * 4096 + wv * 1024);
                __builtin_amdgcn_global_load_lds((glb_u32*)gp, lp, 16, 0, 0);
            }
        }
        // ---- stage A tile: 34,560 B, swizzled source pick ----
        #pragma unroll
        for (int i = 0; i < 9; ++i) {
            const int f = i * 4096 + t * 16;
            if (f < STAGE_B) {
                const int p   = f / LP_PLANE;
                const int r1  = f - p * LP_PLANE;
                const int row = r1 / LP_ROW;
                const int r2  = r1 - row * LP_ROW;
                const int px  = r2 >> 6;
                const int c8s = (r2 >> 4) & 3;
                const int c8  = c8s ^ (px & 3) ^ ((px >> 2) & 3);
                const char* gp = pwin + (size_t)p * PLANE_B + row * ROWB + px * 128 + cc * 64 + c8 * 16;
                lds_u32* lp = (lds_u32*)(tile + i * 4096 + wv * 1024);
                __builtin_amdgcn_global_load_lds((glb_u32*)gp, lp, 16, 0, 0);
            }
        }
        __syncthreads();

        // ---- 3 kx-steps: 6 B + 12 A ds_reads + 36 MFMA per wave (zero vmcnt) ----
        #pragma unroll
        for (int kx = 0; kx < 3; ++kx) {
            s16x8 bf[3][2];
            #pragma unroll
            for (int ky = 0; ky < 3; ++ky)
                #pragma unroll
                for (int ntl = 0; ntl < 2; ++ntl)
                    bf[ky][ntl] = *(const s16x8*)&ldsw[(((ky * 3 + kx) * 2 + ntl) << 10) + lane * 16];
            const int pxr  = m + kx;
            const int c8sr = q ^ (pxr & 3) ^ ((pxr >> 2) & 3);
            const int abase = wv * (2 * LP_ROW) + pxr * 64 + c8sr * 16;
            s16x8 af[4][3];
            #pragma unroll
            for (int r4 = 0; r4 < 4; ++r4)
                #pragma unroll
                for (int p = 0; p < 3; ++p)
                    af[r4][p] = *(const s16x8*)&tile[abase + r4 * LP_ROW + p * LP_PLANE];
            #pragma unroll
            for (int ky = 0; ky < 3; ++ky)
                #pragma unroll
                for (int at = 0; at < 2; ++at)
                    #pragma unroll
                    for (int p = 0; p < 3; ++p)
                        #pragma unroll
                        for (int ntl = 0; ntl < 2; ++ntl)
                            acc[p][at][ntl] = __builtin_amdgcn_mfma_f32_16x16x32_bf16(
                                af[at + ky][p], bf[ky][ntl], acc[p][at][ntl], 0, 0, 0);
        }
    }

    // ---- epilogue: telescoped diffs, f32x2 packed; D: n = lane&15, px = q*4+reg ----
    #pragma unroll
    for (int ntl = 0; ntl < 2; ++ntl) {
        const int o = (oc2 * 2 + ntl) * 16 + (lane & 15);
        const float Sv = S[o];
        const float fS = -0.000287f / 75.f * Sv;
        const float cg1 = 0.8448f  + 0.001309f * Sv;
        const float D1  = 0.52992f - 0.003809f * Sv;
        const float D2  = 0.45312f + 0.001546f * Sv;
        const float D3  = 1.152f   - 0.006386f * Sv;
        const float D4  = 0.91392f - 0.00283f  * Sv;
        #pragma unroll
        for (int at = 0; at < 2; ++at) {
            float res[4];
            #pragma unroll
            for (int h = 0; h < 2; ++h) {
                const f32x2 u1 = {acc[0][at][ntl][2 * h], acc[0][at][ntl][2 * h + 1]};
                const f32x2 u2 = {acc[1][at][ntl][2 * h], acc[1][at][ntl][2 * h + 1]};
                const f32x2 u3 = {acc[2][at][ntl][2 * h], acc[2][at][ntl][2 * h + 1]};
                const f32x2 f  = fS   + 0.00354667f * u1 - 0.00146267f * u2;
                const f32x2 g1 = cg1  + 0.00619f    * u1 - 0.009f      * u2 + 0.001383f * u3;
                const f32x2 d1 = D1   - 0.00316f    * u1 + 0.00416f    * u2 + 0.016117f * u3;
                const f32x2 d2 = D2   - 0.00116f    * u1 + 0.006717f   * u2 - 0.00248f  * u3;
                const f32x2 d3 = D3   - 0.000753f   * u1 + 0.005643f   * u2 - 0.00602f  * u3;
                const f32x2 d4 = D4   - 0.000691f   * u1 + 0.00085f    * u2 - 0.00487f  * u3;
                f32x2 E;
                E.x = __expf(-10.f * f.x);
                E.y = __expf(-10.f * f.y);
                const f32x2 den1 = 1.f + E * 4.4816890703f;
                const f32x2 den2 = 1.f + E * 9.9741824548f;
                const f32x2 den3 = 1.f + E * 24.5325301971f;
                const f32x2 den4 = 1.f + E * 49.4024491055f;
                f32x2 o2 = g1;
                o2.x += __builtin_amdgcn_rcpf(den1.x) * d1.x + __builtin_amdgcn_rcpf(den2.x) * d2.x
                      + __builtin_amdgcn_rcpf(den3.x) * d3.x + __builtin_amdgcn_rcpf(den4.x) * d4.x;
                o2.y += __builtin_amdgcn_rcpf(den1.y) * d1.y + __builtin_amdgcn_rcpf(den2.y) * d2.y
                      + __builtin_amdgcn_rcpf(den3.y) * d3.y + __builtin_amdgcn_rcpf(den4.y) * d4.y;
                res[2 * h] = o2.x; res[2 * h + 1] = o2.y;
            }
            const int y = y0 + 2 * wv + at;
            float* op = out + (((size_t)(b * 64 + o)) * HW + y) * HW + x0 + q * 4;
            *(float4*)op = make_float4(res[0], res[1], res[2], res[3]);
        }
    }
}

extern "C" void kernel_launch(void* const* d_in, const int* in_sizes, int n_in,
                              void* d_out, int out_size, void* d_ws, size_t ws_size,
                              hipStream_t stream) {
    const float* img = (const float*)d_in[0];
    const float* w   = (const float*)d_in[1];
    float* outp = (float*)d_out;
    unsigned short* pw = (unsigned short*)d_ws;
    unsigned short* wb = pw + WB_OFF_SH;
    float* S = (float*)(pw + S_OFF_SH);

    hipLaunchKernelGGL(prep_pow,  dim3(1065), dim3(256), 0, stream, img, w, pw, wb, S);
    hipLaunchKernelGGL(conv_main, dim3(1568), dim3(256), 0, stream, pw, wb, S, outp);
}